// Round 11
// baseline (367.540 us; speedup 1.0000x reference)
//
#include <hip/hip_runtime.h>
#include <hip/hip_bf16.h>

// BGraphAttentionLayer: fused GAT layer, never materializes the 8192^2 attention.
// hp1 = E @ (Wh2/Z2), hp2 = E^T @ (Wh1/Z1), E = adj>0 ? exp(lrelu(s1_i+s2_j)) : 0.
// adj enters only via sign -> one pure-streaming coalesced sweep builds an 8MB
// bitmask; Z1/Z2 and the two MFMA sweeps recompute E from (mask, s1, s2).
// V matrices are pre-packed in MFMA-B-fragment order so every hp B-load is a
// fully coalesced 16B/lane load. hp outputs via split-K partials (plain
// stores) + strip-sum epilogue. s1/s2 pre-scaled by log2(e); E-gen uses raw
// v_exp_f32. NOTE: k_mask is launched 3x this round as a timing diagnostic
// (idempotent): total-time delta vs r10 measures k_mask's true duration.

#define N 8192
#define FIN 256
#define FOUT 64
#define NSTRIP 8
#define HPSZ ((size_t)N * FOUT)  // 524288 floats per partial strip

typedef float f32x4 __attribute__((ext_vector_type(4)));
typedef short s16x8 __attribute__((ext_vector_type(8)));
typedef unsigned short u16;
typedef unsigned long long u64;

#if __has_builtin(__builtin_amdgcn_exp2f)
#define EXP2(x) __builtin_amdgcn_exp2f(x)
#else
#define EXP2(x) exp2f(x)
#endif

__device__ __forceinline__ u16 f2bf(float x) {
  unsigned u = __builtin_bit_cast(unsigned, x);
  return (u16)((u + 0x7FFFu + ((u >> 16) & 1u)) >> 16);  // RTNE
}
__device__ __forceinline__ u16 f2bf_t(float x) {  // truncating (cheap)
  return (u16)(__builtin_bit_cast(unsigned, x) >> 16);
}
// x is already scaled by log2(e): exp(lrelu(y)) == exp2(max(x, 0.2x))
__device__ __forceinline__ float lrexp2(float x) {
  return EXP2(fmaxf(x, 0.2f * x));
}

// ------- K1: Wh1/Wh2 ([N][64], coalesced stores) + s1/s2 + Z2 zero -------
__global__ __launch_bounds__(256) void k_prep(
    const float* __restrict__ h1, const float* __restrict__ h2,
    const float* __restrict__ W1, const float* __restrict__ W2,
    const float* __restrict__ a,
    float* __restrict__ Wh1, float* __restrict__ Wh2,
    float* __restrict__ s1, float* __restrict__ s2, float* __restrict__ Z2z) {
  __shared__ float hbuf[16][FIN];
  const int t = threadIdx.x;
  const int r0 = blockIdx.x * 16;
  const int f = t & 63, q = t >> 6;
  const int lrow = t >> 4, lc0 = (t & 15) * 16;
  {
    const int g = blockIdx.x * 256 + t;
    if (g < 2048)
      *(f32x4*)(Z2z + g * 4) = f32x4{0.f, 0.f, 0.f, 0.f};
  }
  for (int mat = 0; mat < 2; ++mat) {
    const float* h = mat ? h2 : h1;
    const float* W = mat ? W2 : W1;
    float* Wh = mat ? Wh2 : Wh1;
    float* so = mat ? s2 : s1;
    const float av = a[mat * FOUT + f];
    __syncthreads();
    const float* src = h + (size_t)(r0 + lrow) * FIN + lc0;
#pragma unroll
    for (int u = 0; u < 4; ++u)
      *(f32x4*)&hbuf[lrow][lc0 + u * 4] = *(const f32x4*)(src + u * 4);
    __syncthreads();
    float acc[4] = {0.f, 0.f, 0.f, 0.f};
    for (int k = 0; k < FIN; ++k) {
      float wv = W[k * FOUT + f];
#pragma unroll
      for (int rg = 0; rg < 4; ++rg)
        acc[rg] = fmaf(hbuf[rg * 4 + q][k], wv, acc[rg]);
    }
#pragma unroll
    for (int rg = 0; rg < 4; ++rg) {
      int r = r0 + rg * 4 + q;
      Wh[(size_t)r * FOUT + f] = acc[rg];  // coalesced (was 64-line scatter)
      float sp = acc[rg] * av;
#pragma unroll
      for (int m = 1; m < 64; m <<= 1) sp += __shfl_xor(sp, m, 64);
      if (f == 0) so[r] = sp * 1.4426950408889634f;  // fold log2(e)
    }
  }
}

// ---- K2: coalesced sign sweep -> bitmask (the only 256MB read) ----
// grid (8 col-stripes of 1024, 256 row-chunks of 32). Lane owns 4 consecutive
// cols (16B/lane, 1KB/wave contiguous). 2-deep row-group pipeline, named regs
// only (r7 PROC_ROW precedent: bounded live set, no spill).
#define MLOAD(rr, V0, V1, V2, V3)                              \
  V0 = *(const f32x4*)(adj + (size_t)((rr) + 0) * N + c0);     \
  V1 = *(const f32x4*)(adj + (size_t)((rr) + 1) * N + c0);     \
  V2 = *(const f32x4*)(adj + (size_t)((rr) + 2) * N + c0);     \
  V3 = *(const f32x4*)(adj + (size_t)((rr) + 3) * N + c0);

#define MPROC(rr, V0, V1, V2, V3)                                            \
  {                                                                          \
    unsigned nibs = 0;                                                       \
    _Pragma("unroll") for (int e = 0; e < 4; ++e) {                          \
      nibs |= (V0[e] > 0.f ? 1u : 0u) << e;                                  \
      nibs |= (V1[e] > 0.f ? 1u : 0u) << (8 + e);                            \
      nibs |= (V2[e] > 0.f ? 1u : 0u) << (16 + e);                           \
      nibs |= (V3[e] > 0.f ? 1u : 0u) << (24 + e);                           \
    }                                                                        \
    const unsigned n0 = __shfl(nibs, srcb + 0, 64);                          \
    const unsigned n1 = __shfl(nibs, srcb + 1, 64);                          \
    const unsigned n2 = __shfl(nibs, srcb + 2, 64);                          \
    const unsigned n3 = __shfl(nibs, srcb + 3, 64);                          \
    const int sh = 8 * r;                                                    \
    const unsigned word = ((n0 >> sh) & 0xFu) | (((n1 >> sh) & 0xFu) << 4) | \
                          (((n2 >> sh) & 0xFu) << 8) |                       \
                          (((n3 >> sh) & 0xFu) << 12);                       \
    mbase[(size_t)((rr) + r) * 512] = (u16)word;                             \
  }

__global__ __launch_bounds__(256) void k_mask(const float* __restrict__ adj,
                                              u16* __restrict__ mask) {
  const int t = threadIdx.x;
  const int wv = t >> 6, ln = t & 63;
  const int sb = blockIdx.x * 1024;
  const int r0 = blockIdx.y * 32;
  const int c0 = sb + wv * 256 + ln * 4;
  const int r = ln >> 4, wl = ln & 15;
  const int srcb = wl * 4;
  u16* mbase = mask + (sb >> 4) + wv * 16 + wl;
  f32x4 A0, A1, A2, A3, B0, B1, B2, B3;
  MLOAD(r0, A0, A1, A2, A3);
#pragma unroll 1
  for (int g = 0; g < 8; g += 2) {
    MLOAD(r0 + g * 4 + 4, B0, B1, B2, B3);
    MPROC(r0 + g * 4, A0, A1, A2, A3);
    if (g + 2 < 8) {
      MLOAD(r0 + g * 4 + 8, A0, A1, A2, A3);
    }
    MPROC(r0 + g * 4 + 4, B0, B1, B2, B3);
  }
}

// ------- K2b: Z1 (blocks 0..2047, 4 rows each) + Z2 (blocks 2048..2559) -------
__global__ __launch_bounds__(256) void k_zboth(const u16* __restrict__ maskp,
                                               const float* __restrict__ s1,
                                               const float* __restrict__ s2,
                                               float* __restrict__ Z1,
                                               float* __restrict__ Z2) {
  const int t = threadIdx.x, lane = t & 63, wv = t >> 6;
  const int b = blockIdx.x;
  if (b < 2048) {
    // Z1: row sums, 4 rows per block, no atomics
    const int r0 = b * 4;
    __shared__ float part[4][4];
#pragma unroll 1
    for (int rr = 0; rr < 4; ++rr) {
      const int row = r0 + rr;
      const u64* mrow = (const u64*)maskp + (size_t)row * 128;
      const float s1v = s1[row];
      float z = 0.f;
#pragma unroll 2
      for (int k = 0; k < 32; ++k) {
        const u64 word = mrow[wv + 4 * k];  // wave-uniform -> broadcast
        const float s2v = s2[t + 256 * k];  // coalesced, L1-hot after rr=0
        const float ev = lrexp2(s1v + s2v);
        z += ((word >> lane) & 1ull) ? ev : 0.f;
      }
#pragma unroll
      for (int sh = 1; sh < 64; sh <<= 1) z += __shfl_xor(z, sh, 64);
      if (lane == 0) part[wv][rr] = z;
    }
    __syncthreads();
    if (t < 4)
      Z1[r0 + t] = part[0][t] + part[1][t] + part[2][t] + part[3][t];
  } else {
    // Z2: col sums, strip atomics (512 blocks, 131K atomics total)
    const int b2 = b - 2048;
    const int j = (b2 & 31) * 256 + t;
    const int i0 = (b2 >> 5) * 512;
    const u64* m64 = (const u64*)maskp + (j >> 6);
    const float s2v = s2[j];
    float z = 0.f;
#pragma unroll 2
    for (int i = i0; i < i0 + 512; ++i) {
      const u64 word = m64[(size_t)i * 128];  // wave-uniform -> broadcast
      const float ev = lrexp2(s1[i] + s2v);
      z += ((word >> lane) & 1ull) ? ev : 0.f;
    }
    atomicAdd(&Z2[j], z);
  }
}

// ---- K3: V{1,2}P = (Wh/Z) pre-packed in MFMA-B-fragment order (bf16) ----
// Fragment (jb, kk, nt, lane) holds 8 consecutive u16: element e is
// Wh[j = jb*64 + kk*32 + (lane>>4)*8 + e][f = nt*16 + (lane&15)] / Z[j].
__global__ __launch_bounds__(256) void k_buildv(
    const float* __restrict__ Wh1, const float* __restrict__ Wh2,
    const float* __restrict__ Z1, const float* __restrict__ Z2,
    u16* __restrict__ V1P, u16* __restrict__ V2P) {
  const int mat = blockIdx.y;
  const float* Wh = mat ? Wh2 : Wh1;
  const float* Z = mat ? Z2 : Z1;
  u16* VP = mat ? V2P : V1P;
  const int g = blockIdx.x * 256 + threadIdx.x;
  const int lane = g & 63, nt = (g >> 6) & 3, kk = (g >> 8) & 1, jb = g >> 9;
  const int j = jb * 64 + kk * 32 + (lane >> 4) * 8;
  const int f = nt * 16 + (lane & 15);
  const float* wp = Wh + (size_t)j * FOUT + f;  // stride-FOUT gather (L2-hot)
  const float w0 = wp[0 * FOUT], w1 = wp[1 * FOUT];
  const float w2 = wp[2 * FOUT], w3 = wp[3 * FOUT];
  const float w4 = wp[4 * FOUT], w5 = wp[5 * FOUT];
  const float w6 = wp[6 * FOUT], w7 = wp[7 * FOUT];
  const f32x4 za = *(const f32x4*)(Z + j);
  const f32x4 zb = *(const f32x4*)(Z + j + 4);
  uint4 o;
  o.x = (unsigned)f2bf(w0 / za.x) | ((unsigned)f2bf(w1 / za.y) << 16);
  o.y = (unsigned)f2bf(w2 / za.z) | ((unsigned)f2bf(w3 / za.w) << 16);
  o.z = (unsigned)f2bf(w4 / zb.x) | ((unsigned)f2bf(w5 / zb.y) << 16);
  o.w = (unsigned)f2bf(w6 / zb.z) | ((unsigned)f2bf(w7 / zb.w) << 16);
  *(uint4*)(VP + (size_t)g * 8) = o;
}

// -- K4: merged hp kernels. z=0: hp1 partial = E@V2 over j-strip.
//        z=1: hp2 partial = E^T@V1 over i-strip. Plain stores, no atomics.
// grid (64 chunks of 128, NSTRIP strips of 1024, 2).
__global__ __launch_bounds__(256, 2) void k_hp(
    const u16* __restrict__ maskp, const float* __restrict__ s1g,
    const float* __restrict__ s2g, const u16* __restrict__ V1P,
    const u16* __restrict__ V2P, float* __restrict__ hp1P,
    float* __restrict__ hp2P) {
  const int t = threadIdx.x, w = t >> 6, lane = t & 63;
  const int l15 = lane & 15, l4 = lane >> 4;
  const int sh0 = l4 * 8;
  f32x4 acc[2][4];
#pragma unroll
  for (int mt = 0; mt < 2; ++mt)
#pragma unroll
    for (int nt = 0; nt < 4; ++nt) acc[mt][nt] = f32x4{0.f, 0.f, 0.f, 0.f};

  if (blockIdx.z == 0) {
    // ---------------- hp1: rows i, K-axis j ----------------
    const int i0 = blockIdx.x * 128 + w * 32;
    const int jbase = blockIdx.y * 1024;
    const u64* mrow0 = (const u64*)maskp + (size_t)(i0 + l15) * 128;
    const u64* mrow1 = mrow0 + 16 * 128;
    const float s1v0 = s1g[i0 + l15];
    const float s1v1 = s1g[i0 + 16 + l15];
#pragma unroll 2
    for (int js = 0; js < 16; ++js) {
      const int j0s = jbase + js * 64;
      const u64 m0 = mrow0[j0s >> 6];
      const u64 m1 = mrow1[j0s >> 6];
      f32x4 s2q[4];
#pragma unroll
      for (int kk = 0; kk < 2; ++kk)
#pragma unroll
        for (int h = 0; h < 2; ++h)
          s2q[kk * 2 + h] = *(const f32x4*)(s2g + j0s + kk * 32 + sh0 + h * 4);
      s16x8 afr[2][2];  // [mt][kk]
#pragma unroll
      for (int kk = 0; kk < 2; ++kk) {
        const unsigned b0 = (unsigned)(kk ? (m0 >> 32) : m0);
        const unsigned b1 = (unsigned)(kk ? (m1 >> 32) : m1);
#pragma unroll
        for (int e = 0; e < 8; ++e) {
          const float s2e = s2q[kk * 2 + (e >> 2)][e & 3];
          float e0 = lrexp2(s1v0 + s2e);
          float e1 = lrexp2(s1v1 + s2e);
          e0 = ((b0 >> (sh0 + e)) & 1u) ? e0 : 0.f;
          e1 = ((b1 >> (sh0 + e)) & 1u) ? e1 : 0.f;
          afr[0][kk][e] = (short)f2bf_t(e0);
          afr[1][kk][e] = (short)f2bf_t(e1);
        }
      }
      const u16* vb = V2P + (((size_t)(j0s >> 6) * 8) << 9) + lane * 8;
#pragma unroll
      for (int half = 0; half < 2; ++half) {
        const int n0 = half * 2, n1 = half * 2 + 1;
        const s16x8 bf00 = *(const s16x8*)(vb + ((0 * 4 + n0) << 9));
        const s16x8 bf01 = *(const s16x8*)(vb + ((0 * 4 + n1) << 9));
        const s16x8 bf10 = *(const s16x8*)(vb + ((1 * 4 + n0) << 9));
        const s16x8 bf11 = *(const s16x8*)(vb + ((1 * 4 + n1) << 9));
        acc[0][n0] = __builtin_amdgcn_mfma_f32_16x16x32_bf16(afr[0][0], bf00,
                                                             acc[0][n0], 0, 0, 0);
        acc[0][n0] = __builtin_amdgcn_mfma_f32_16x16x32_bf16(afr[0][1], bf10,
                                                             acc[0][n0], 0, 0, 0);
        acc[0][n1] = __builtin_amdgcn_mfma_f32_16x16x32_bf16(afr[0][0], bf01,
                                                             acc[0][n1], 0, 0, 0);
        acc[0][n1] = __builtin_amdgcn_mfma_f32_16x16x32_bf16(afr[0][1], bf11,
                                                             acc[0][n1], 0, 0, 0);
        acc[1][n0] = __builtin_amdgcn_mfma_f32_16x16x32_bf16(afr[1][0], bf00,
                                                             acc[1][n0], 0, 0, 0);
        acc[1][n0] = __builtin_amdgcn_mfma_f32_16x16x32_bf16(afr[1][1], bf10,
                                                             acc[1][n0], 0, 0, 0);
        acc[1][n1] = __builtin_amdgcn_mfma_f32_16x16x32_bf16(afr[1][0], bf01,
                                                             acc[1][n1], 0, 0, 0);
        acc[1][n1] = __builtin_amdgcn_mfma_f32_16x16x32_bf16(afr[1][1], bf11,
                                                             acc[1][n1], 0, 0, 0);
      }
    }
    float* dst = hp1P + (size_t)blockIdx.y * HPSZ;
#pragma unroll
    for (int mt = 0; mt < 2; ++mt)
#pragma unroll
      for (int nt = 0; nt < 4; ++nt)
#pragma unroll
        for (int r = 0; r < 4; ++r)
          dst[(size_t)(i0 + mt * 16 + l4 * 4 + r) * 64 + nt * 16 + l15] =
              acc[mt][nt][r];
  } else {
    // ---------------- hp2: rows j, K-axis i ----------------
    const int j0w = blockIdx.x * 128 + w * 32;
    const int ibase = blockIdx.y * 1024;
    const float s2vA = s2g[j0w + l15];
    const float s2vB = s2g[j0w + 16 + l15];
    const unsigned* mask32 = (const unsigned*)maskp;
    const int wsel = j0w >> 5;
#pragma unroll 2
    for (int tile = 0; tile < 16; ++tile) {
      const int it0 = ibase + tile * 64;
      f32x4 s1q[4];
#pragma unroll
      for (int kk = 0; kk < 2; ++kk)
#pragma unroll
        for (int h = 0; h < 2; ++h)
          s1q[kk * 2 + h] = *(const f32x4*)(s1g + it0 + kk * 32 + sh0 + h * 4);
      unsigned mw[2][8];
#pragma unroll
      for (int kk = 0; kk < 2; ++kk)
#pragma unroll
        for (int e = 0; e < 8; ++e)
          mw[kk][e] = mask32[(size_t)(it0 + kk * 32 + sh0 + e) * 256 + wsel];
      s16x8 aA[2], aB[2];
#pragma unroll
      for (int kk = 0; kk < 2; ++kk)
#pragma unroll
        for (int e = 0; e < 8; ++e) {
          const float s1v = s1q[kk * 2 + (e >> 2)][e & 3];
          float eA = lrexp2(s1v + s2vA);
          float eB = lrexp2(s1v + s2vB);
          const unsigned mwv = mw[kk][e];
          eA = ((mwv >> l15) & 1u) ? eA : 0.f;
          eB = ((mwv >> (16 + l15)) & 1u) ? eB : 0.f;
          aA[kk][e] = (short)f2bf_t(eA);
          aB[kk][e] = (short)f2bf_t(eB);
        }
      const u16* vb = V1P + (((size_t)(it0 >> 6) * 8) << 9) + lane * 8;
#pragma unroll
      for (int half = 0; half < 2; ++half) {
        const int n0 = half * 2, n1 = half * 2 + 1;
        const s16x8 bf00 = *(const s16x8*)(vb + ((0 * 4 + n0) << 9));
        const s16x8 bf01 = *(const s16x8*)(vb + ((0 * 4 + n1) << 9));
        const s16x8 bf10 = *(const s16x8*)(vb + ((1 * 4 + n0) << 9));
        const s16x8 bf11 = *(const s16x8*)(vb + ((1 * 4 + n1) << 9));
        acc[0][n0] = __builtin_amdgcn_mfma_f32_16x16x32_bf16(aA[0], bf00,
                                                             acc[0][n0], 0, 0, 0);
        acc[0][n0] = __builtin_amdgcn_mfma_f32_16x16x32_bf16(aA[1], bf10,
                                                             acc[0][n0], 0, 0, 0);
        acc[0][n1] = __builtin_amdgcn_mfma_f32_16x16x32_bf16(aA[0], bf01,
                                                             acc[0][n1], 0, 0, 0);
        acc[0][n1] = __builtin_amdgcn_mfma_f32_16x16x32_bf16(aA[1], bf11,
                                                             acc[0][n1], 0, 0, 0);
        acc[1][n0] = __builtin_amdgcn_mfma_f32_16x16x32_bf16(aB[0], bf00,
                                                             acc[1][n0], 0, 0, 0);
        acc[1][n0] = __builtin_amdgcn_mfma_f32_16x16x32_bf16(aB[1], bf10,
                                                             acc[1][n0], 0, 0, 0);
        acc[1][n1] = __builtin_amdgcn_mfma_f32_16x16x32_bf16(aB[0], bf01,
                                                             acc[1][n1], 0, 0, 0);
        acc[1][n1] = __builtin_amdgcn_mfma_f32_16x16x32_bf16(aB[1], bf11,
                                                             acc[1][n1], 0, 0, 0);
      }
    }
    float* dst = hp2P + (size_t)blockIdx.y * HPSZ;
#pragma unroll
    for (int mt = 0; mt < 2; ++mt)
#pragma unroll
      for (int nt = 0; nt < 4; ++nt)
#pragma unroll
        for (int r = 0; r < 4; ++r)
          dst[(size_t)(j0w + mt * 16 + l4 * 4 + r) * 64 + nt * 16 + l15] =
              acc[mt][nt][r];
  }
}

// ------- K5: strip-sum + ELU epilogue for both outputs -------
__global__ __launch_bounds__(256) void k_red(const float* __restrict__ hp1P,
                                             const float* __restrict__ hp2P,
                                             float* __restrict__ out) {
  const size_t idx = ((size_t)blockIdx.x * 256 + threadIdx.x) * 4;
  f32x4 a1 = f32x4{0.f, 0.f, 0.f, 0.f};
  f32x4 a2 = f32x4{0.f, 0.f, 0.f, 0.f};
#pragma unroll 4
  for (int s = 0; s < NSTRIP; ++s) {
    a1 += *(const f32x4*)(hp1P + s * HPSZ + idx);
    a2 += *(const f32x4*)(hp2P + s * HPSZ + idx);
  }
  f32x4 o1, o2;
#pragma unroll
  for (int c = 0; c < 4; ++c) {
    o1[c] = a1[c] > 0.f ? a1[c] : expm1f(a1[c]);
    o2[c] = a2[c] > 0.f ? a2[c] : expm1f(a2[c]);
  }
  *(f32x4*)(out + idx) = o1;
  *(f32x4*)(out + (size_t)N * FOUT + idx) = o2;
}

extern "C" void kernel_launch(void* const* d_in, const int* in_sizes, int n_in,
                              void* d_out, int out_size, void* d_ws,
                              size_t ws_size, hipStream_t stream) {
  const float* h1 = (const float*)d_in[0];
  const float* h2 = (const float*)d_in[1];
  const float* adj = (const float*)d_in[2];
  const float* W1 = (const float*)d_in[3];
  const float* W2 = (const float*)d_in[4];
  const float* a = (const float*)d_in[5];

  float* ws = (float*)d_ws;
  // float-offset workspace layout (~48 MB total)
  float* s1 = ws + 0;
  float* s2 = ws + 8192;
  float* Z1 = ws + 16384;
  float* Z2 = ws + 24576;
  float* Wh1 = ws + 32768;                // [8192][64] f32
  float* Wh2 = ws + 557056;
  u16* V1P = (u16*)(ws + 1081344);        // fragment-packed bf16, 1 MB
  u16* V2P = (u16*)(ws + 1343488);
  u16* mask = (u16*)(ws + 1605632);       // [8192][512] u16 = 8 MB bitmask
  float* hp1P = ws + 3702784;             // [NSTRIP][8192][64] f32 = 16 MB
  float* hp2P = hp1P + NSTRIP * HPSZ;     // [NSTRIP][8192][64] f32 = 16 MB

  k_prep<<<512, 256, 0, stream>>>(h1, h2, W1, W2, a, Wh1, Wh2, s1, s2, Z2);
  // DIAGNOSTIC: k_mask launched 3x (idempotent). Total-time delta vs round 10
  // measures k_mask's true per-launch duration.
  k_mask<<<dim3(8, 256), 256, 0, stream>>>(adj, mask);
  k_mask<<<dim3(8, 256), 256, 0, stream>>>(adj, mask);
  k_mask<<<dim3(8, 256), 256, 0, stream>>>(adj, mask);
  k_zboth<<<2560, 256, 0, stream>>>(mask, s1, s2, Z1, Z2);
  k_buildv<<<dim3(256, 2), 256, 0, stream>>>(Wh1, Wh2, Z1, Z2, V1P, V2P);
  k_hp<<<dim3(64, NSTRIP, 2), 256, 0, stream>>>(mask, s1, s2, V1P, V2P, hp1P,
                                                hp2P);
  k_red<<<512, 256, 0, stream>>>(hp1P, hp2P, (float*)d_out);
}